// Round 1
// baseline (579.740 us; speedup 1.0000x reference)
//
#include <hip/hip_runtime.h>

// GraphSAGE: agg = segment_mean(x[src] -> dst); out = relu(x@Ws + bs + agg@Wn + bn)
// N=100000, D_IN=D_OUT=64, E=1600000

#define D 64

// One wave (64 lanes) per edge; lane = feature index.
__global__ __launch_bounds__(256) void edge_scatter(
    const float* __restrict__ x, const int* __restrict__ ei,
    float* __restrict__ agg, float* __restrict__ deg, int E) {
  int gid  = blockIdx.x * blockDim.x + threadIdx.x;
  int lane = threadIdx.x & 63;
  int wave = gid >> 6;
  int nwaves = (gridDim.x * blockDim.x) >> 6;
  for (int e = wave; e < E; e += nwaves) {
    int s = ei[e];        // src row
    int d = ei[E + e];    // dst row
    float v = x[(long)s * D + lane];
    atomicAdd(&agg[(long)d * D + lane], v);
    if (lane == 0) atomicAdd(&deg[d], 1.0f);
  }
}

// Fused: agg/deg normalize + x@Ws + agg@Wn + bias + relu.
// Block = 256 threads = 4 waves; wave per node, lane per output feature.
__global__ __launch_bounds__(256) void sage_out(
    const float* __restrict__ x, const float* __restrict__ agg,
    const float* __restrict__ deg,
    const float* __restrict__ Wself, const float* __restrict__ bself,
    const float* __restrict__ Wneigh, const float* __restrict__ bneigh,
    float* __restrict__ out, int N) {
  __shared__ float sWs[D * D];   // 16 KB
  __shared__ float sWn[D * D];   // 16 KB
  __shared__ float sx[4][D];
  __shared__ float sa[4][D];

  int t = threadIdx.x;
  for (int i = t; i < D * D; i += 256) {
    sWs[i] = Wself[i];
    sWn[i] = Wneigh[i];
  }
  int lane = t & 63;
  int w = t >> 6;
  float bias = bself[lane] + bneigh[lane];
  __syncthreads();

  for (int n0 = blockIdx.x * 4; n0 < N; n0 += gridDim.x * 4) {
    int n = n0 + w;
    if (n < N) {
      sx[w][lane] = x[(long)n * D + lane];
      float dg = deg[n];
      dg = dg < 1.0f ? 1.0f : dg;
      sa[w][lane] = agg[(long)n * D + lane] * (1.0f / dg);
    }
    __syncthreads();
    if (n < N) {
      float acc = bias;
#pragma unroll
      for (int k = 0; k < D; ++k) {
        acc = fmaf(sx[w][k], sWs[k * D + lane], acc);
        acc = fmaf(sa[w][k], sWn[k * D + lane], acc);
      }
      out[(long)n * D + lane] = acc > 0.0f ? acc : 0.0f;
    }
    __syncthreads();
  }
}

extern "C" void kernel_launch(void* const* d_in, const int* in_sizes, int n_in,
                              void* d_out, int out_size, void* d_ws, size_t ws_size,
                              hipStream_t stream) {
  const float* x      = (const float*)d_in[0];
  const int*   ei     = (const int*)d_in[1];
  const float* Wself  = (const float*)d_in[2];
  const float* bself  = (const float*)d_in[3];
  const float* Wneigh = (const float*)d_in[4];
  const float* bneigh = (const float*)d_in[5];

  int N = in_sizes[0] / D;
  int E = in_sizes[1] / 2;

  float* agg = (float*)d_ws;                 // N*64 floats
  float* deg = agg + (size_t)N * D;          // N floats

  hipMemsetAsync(d_ws, 0, ((size_t)N * D + N) * sizeof(float), stream);
  edge_scatter<<<8192, 256, 0, stream>>>(x, ei, agg, deg, E);
  sage_out<<<2048, 256, 0, stream>>>(x, agg, deg, Wself, bself, Wneigh, bneigh,
                                     (float*)d_out, N);
}

// Round 2
// 379.676 us; speedup vs baseline: 1.5269x; 1.5269x over previous
//
#include <hip/hip_runtime.h>

// GraphSAGE: agg = segment_mean(x[src] -> dst); out = relu(x@Ws + bs + agg@Wn + bn)
// N=100000, D_IN=D_OUT=64, E=1600000
// Strategy: CSR counting-sort (no feature-space atomics), then gather-aggregate,
// then LDS-tiled fp32 GEMM.

#define D 64

// ---------- pass 1: degree count ----------
__global__ __launch_bounds__(256) void count_deg(const int* __restrict__ dst,
                                                 int* __restrict__ cnt, int E) {
  int tid = blockIdx.x * blockDim.x + threadIdx.x;
  int stride = gridDim.x * blockDim.x;
  int E4 = E >> 2;
  const int4* d4 = (const int4*)dst;
  for (int i = tid; i < E4; i += stride) {
    int4 v = d4[i];
    atomicAdd(&cnt[v.x], 1);
    atomicAdd(&cnt[v.y], 1);
    atomicAdd(&cnt[v.z], 1);
    atomicAdd(&cnt[v.w], 1);
  }
  for (int e = (E4 << 2) + tid; e < E; e += stride) atomicAdd(&cnt[dst[e]], 1);
}

// ---------- pass 2: scan (chunk=512) ----------
__global__ __launch_bounds__(512) void chunk_sums(const int* __restrict__ cnt,
                                                  int* __restrict__ chunkSum, int N) {
  int idx = blockIdx.x * 512 + threadIdx.x;
  int c = idx < N ? cnt[idx] : 0;
  for (int o = 1; o < 64; o <<= 1) c += __shfl_xor(c, o, 64);
  __shared__ int ws[8];
  if ((threadIdx.x & 63) == 0) ws[threadIdx.x >> 6] = c;
  __syncthreads();
  if (threadIdx.x == 0) {
    int s = 0;
#pragma unroll
    for (int i = 0; i < 8; i++) s += ws[i];
    chunkSum[blockIdx.x] = s;
  }
}

__global__ __launch_bounds__(256) void scan_chunk_sums(const int* __restrict__ chunkSum,
                                                       int* __restrict__ chunkOff,
                                                       int nchunks) {
  int t = threadIdx.x;
  int v = t < nchunks ? chunkSum[t] : 0;
  int inc = v;
  for (int o = 1; o < 64; o <<= 1) {
    int u = __shfl_up(inc, o, 64);
    if ((t & 63) >= o) inc += u;
  }
  __shared__ int wsum[4];
  if ((t & 63) == 63) wsum[t >> 6] = inc;
  __syncthreads();
  int woff = 0;
  for (int i = 0; i < (t >> 6); i++) woff += wsum[i];
  if (t < nchunks) chunkOff[t] = woff + inc - v;  // exclusive
}

__global__ __launch_bounds__(512) void write_rowptr(const int* __restrict__ cnt,
                                                    const int* __restrict__ chunkOff,
                                                    int* __restrict__ rowPtr,
                                                    int* __restrict__ cursor, int N) {
  int t = threadIdx.x;
  int idx = blockIdx.x * 512 + t;
  int c = idx < N ? cnt[idx] : 0;
  int inc = c;
  for (int o = 1; o < 64; o <<= 1) {
    int u = __shfl_up(inc, o, 64);
    if ((t & 63) >= o) inc += u;
  }
  __shared__ int ws[8];
  if ((t & 63) == 63) ws[t >> 6] = inc;
  __syncthreads();
  int woff = 0;
  for (int i = 0; i < (t >> 6); i++) woff += ws[i];
  int excl = chunkOff[blockIdx.x] + woff + inc - c;
  if (idx < N) {
    rowPtr[idx] = excl;
    cursor[idx] = excl;
  }
}

// ---------- pass 3: bucket scatter ----------
__global__ __launch_bounds__(256) void scatter_edges(const int* __restrict__ ei,
                                                     int* __restrict__ cursor,
                                                     int* __restrict__ ssrc, int E) {
  int tid = blockIdx.x * blockDim.x + threadIdx.x;
  int stride = gridDim.x * blockDim.x;
  int E4 = E >> 2;
  const int4* s4 = (const int4*)ei;
  const int4* d4 = (const int4*)(ei + E);
  for (int i = tid; i < E4; i += stride) {
    int4 s = s4[i];
    int4 d = d4[i];
    ssrc[atomicAdd(&cursor[d.x], 1)] = s.x;
    ssrc[atomicAdd(&cursor[d.y], 1)] = s.y;
    ssrc[atomicAdd(&cursor[d.z], 1)] = s.z;
    ssrc[atomicAdd(&cursor[d.w], 1)] = s.w;
  }
  for (int e = (E4 << 2) + tid; e < E; e += stride)
    ssrc[atomicAdd(&cursor[ei[E + e]], 1)] = ei[e];
}

// ---------- pass 4: aggregate (wave per node, lane per feature) ----------
__global__ __launch_bounds__(256) void k_agg(const float* __restrict__ x,
                                             const int* __restrict__ rowPtr,
                                             const int* __restrict__ rowEnd,
                                             const int* __restrict__ ssrc,
                                             float* __restrict__ agg, int N) {
  int gid = blockIdx.x * blockDim.x + threadIdx.x;
  int lane = threadIdx.x & 63;
  int wave = gid >> 6;
  int nwaves = (gridDim.x * blockDim.x) >> 6;
  for (int n = wave; n < N; n += nwaves) {
    int st = rowPtr[n];
    int en = rowEnd[n];  // cursor after scatter == row end
    float a0 = 0.f, a1 = 0.f, a2 = 0.f, a3 = 0.f;
    int i = st;
    for (; i + 4 <= en; i += 4) {
      int s0 = ssrc[i], s1 = ssrc[i + 1], s2 = ssrc[i + 2], s3 = ssrc[i + 3];
      a0 += x[(size_t)s0 * D + lane];
      a1 += x[(size_t)s1 * D + lane];
      a2 += x[(size_t)s2 * D + lane];
      a3 += x[(size_t)s3 * D + lane];
    }
    for (; i < en; i++) a0 += x[(size_t)ssrc[i] * D + lane];
    float sum = (a0 + a1) + (a2 + a3);
    int len = en - st;
    float inv = 1.f / (float)(len > 0 ? len : 1);
    agg[(size_t)n * D + lane] = sum * inv;
  }
}

// ---------- pass 5: GEMM + bias + relu ----------
// Block = 256 threads; 16 nodes per iteration. Thread (jg = t&15, nsel = t>>4)
// computes out[n0+nsel][jg*4 .. jg*4+3]. Weights in LDS read as float4.
#define XPITCH 68  // pad: conflict-free & 16B-aligned rows
__global__ __launch_bounds__(256) void k_gemm(const float* __restrict__ x,
                                              const float* __restrict__ agg,
                                              const float* __restrict__ Ws,
                                              const float* __restrict__ bs,
                                              const float* __restrict__ Wn,
                                              const float* __restrict__ bn,
                                              float* __restrict__ out, int N) {
  __shared__ float sWs[D * D];
  __shared__ float sWn[D * D];
  __shared__ float sx[16 * XPITCH];
  __shared__ float sa[16 * XPITCH];

  int t = threadIdx.x;
  for (int i = t; i < D * D; i += 256) {
    sWs[i] = Ws[i];
    sWn[i] = Wn[i];
  }
  int jg = t & 15;
  int nsel = t >> 4;
  int j0 = jg * 4;
  float b0 = bs[j0 + 0] + bn[j0 + 0];
  float b1 = bs[j0 + 1] + bn[j0 + 1];
  float b2 = bs[j0 + 2] + bn[j0 + 2];
  float b3 = bs[j0 + 3] + bn[j0 + 3];
  __syncthreads();

  for (int n0 = blockIdx.x * 16; n0 < N; n0 += gridDim.x * 16) {
    // stage 16 rows of x and agg
#pragma unroll
    for (int c = 0; c < 4; c++) {
      int idx = c * 256 + t;
      int nn = idx >> 6, kk = idx & 63;
      int g = n0 + nn;
      float xv = 0.f, av = 0.f;
      if (g < N) {
        xv = x[(size_t)g * D + kk];
        av = agg[(size_t)g * D + kk];
      }
      sx[nn * XPITCH + kk] = xv;
      sa[nn * XPITCH + kk] = av;
    }
    __syncthreads();

    int n = n0 + nsel;
    if (n < N) {
      float acc0 = b0, acc1 = b1, acc2 = b2, acc3 = b3;
#pragma unroll
      for (int k4 = 0; k4 < D; k4 += 4) {
        float4 xv = *(const float4*)&sx[nsel * XPITCH + k4];
        float4 av = *(const float4*)&sa[nsel * XPITCH + k4];
#pragma unroll
        for (int u = 0; u < 4; u++) {
          float xs = (&xv.x)[u];
          float as = (&av.x)[u];
          float4 w = *(const float4*)&sWs[(k4 + u) * D + j0];
          float4 v = *(const float4*)&sWn[(k4 + u) * D + j0];
          acc0 = fmaf(xs, w.x, acc0); acc0 = fmaf(as, v.x, acc0);
          acc1 = fmaf(xs, w.y, acc1); acc1 = fmaf(as, v.y, acc1);
          acc2 = fmaf(xs, w.z, acc2); acc2 = fmaf(as, v.z, acc2);
          acc3 = fmaf(xs, w.w, acc3); acc3 = fmaf(as, v.w, acc3);
        }
      }
      float4 r;
      r.x = acc0 > 0.f ? acc0 : 0.f;
      r.y = acc1 > 0.f ? acc1 : 0.f;
      r.z = acc2 > 0.f ? acc2 : 0.f;
      r.w = acc3 > 0.f ? acc3 : 0.f;
      *(float4*)&out[(size_t)n * D + j0] = r;
    }
    __syncthreads();
  }
}

extern "C" void kernel_launch(void* const* d_in, const int* in_sizes, int n_in,
                              void* d_out, int out_size, void* d_ws, size_t ws_size,
                              hipStream_t stream) {
  const float* x      = (const float*)d_in[0];
  const int*   ei     = (const int*)d_in[1];
  const float* Wself  = (const float*)d_in[2];
  const float* bself  = (const float*)d_in[3];
  const float* Wneigh = (const float*)d_in[4];
  const float* bneigh = (const float*)d_in[5];

  int N = in_sizes[0] / D;
  int E = in_sizes[1] / 2;

  // workspace layout (ints then floats)
  int* cnt      = (int*)d_ws;            // N
  int* rowPtr   = cnt + N;               // N
  int* cursor   = rowPtr + N;            // N
  int* chunkSum = cursor + N;            // 256
  int* chunkOff = chunkSum + 256;        // 256
  int* ssrc     = chunkOff + 256;        // E
  float* agg    = (float*)(ssrc + E);    // N*D

  int nchunks = (N + 511) / 512;

  hipMemsetAsync(cnt, 0, (size_t)N * sizeof(int), stream);
  count_deg<<<1024, 256, 0, stream>>>(ei + E, cnt, E);
  chunk_sums<<<nchunks, 512, 0, stream>>>(cnt, chunkSum, N);
  scan_chunk_sums<<<1, 256, 0, stream>>>(chunkSum, chunkOff, nchunks);
  write_rowptr<<<nchunks, 512, 0, stream>>>(cnt, chunkOff, rowPtr, cursor, N);
  scatter_edges<<<2048, 256, 0, stream>>>(ei, cursor, ssrc, E);
  // after scatter, cursor[n] == rowPtr[n+1] (row end)
  k_agg<<<6250, 256, 0, stream>>>(x, rowPtr, cursor, ssrc, agg, N);
  k_gemm<<<2048, 256, 0, stream>>>(x, agg, Wself, bself, Wneigh, bneigh,
                                   (float*)d_out, N);
}